// Round 5
// baseline (265.226 us; speedup 1.0000x reference)
//
#include <hip/hip_runtime.h>
#include <math.h>

// Output = Re(H) as float32, shape (B,8,8) row-major, 64 floats = 16 float4/record.
// H rows 0-3 = [0|I]; rows 4-7 = [L11 | L12], L12 purely imaginary -> Re = 0.
// Re(L11) needs only c1 = cos(sqrt3*kx), c2 = cos(sqrt3/2*kx + 1.5*ky):
//   m00r = -(0.75 + 0.75*c1)        ( = Re(-A00), shared by A_tr/A_bl )
//   offr = -sqrt3/4 * (1 - c1)      ( = Re(-A01) = Re(-A10) )
//   m11r = -(0.25 + 0.25*c1 + c2)   ( = Re(-A11) )
// Quads (q = float4 index within record):
//   q1=(1,0,0,0) q3=(0,1,0,0) q5=(0,0,1,0) q7=(0,0,0,1)
//   q8 =(1.5,0,m00r,offr)  q10=(0,1.5,offr,m11r)
//   q12=(m00r,offr,1.5,0)  q14=(offr,m11r,0,1.5)
//   all other quads zero.

#define SQRT3F 1.73205080756887729f
#define S34F   0.43301270189221933f   // sqrt(3)/4

__global__ void __launch_bounds__(256)
bulk_hamiltonian_real_kernel(const float* __restrict__ k, float4* __restrict__ out,
                             int n4) {
    const int stride = gridDim.x * blockDim.x;
    for (int i = blockIdx.x * blockDim.x + threadIdx.x; i < n4; i += stride) {
        const int b = i >> 4;   // record (batch) index
        const int q = i & 15;   // float4 index within the 64-float record
        float4 v = make_float4(0.0f, 0.0f, 0.0f, 0.0f);
        if (q >= 8) {
            if ((q & 1) == 0) {   // q = 8,10,12,14 : variable quads
                const float kx = k[2 * (size_t)b];
                const float ky = k[2 * (size_t)b + 1];
                const float c1 = cosf(kx * SQRT3F);
                const float c2 = cosf(kx * (0.5f * SQRT3F) + ky * 1.5f);
                const float m00r = -(0.75f + 0.75f * c1);
                const float offr = -S34F * (1.0f - c1);
                const float m11r = -(0.25f + 0.25f * c1 + c2);
                if (q == 8)       v = make_float4(1.5f, 0.0f, m00r, offr);
                else if (q == 10) v = make_float4(0.0f, 1.5f, offr, m11r);
                else if (q == 12) v = make_float4(m00r, offr, 1.5f, 0.0f);
                else              v = make_float4(offr, m11r, 0.0f, 1.5f);
            }
            // q = 9,11,13,15 stay zero
        } else {
            // identity block quads: q1,q3,q5,q7; the rest zero
            if (q == 1)      v.x = 1.0f;
            else if (q == 3) v.y = 1.0f;
            else if (q == 5) v.z = 1.0f;
            else if (q == 7) v.w = 1.0f;
        }
        out[(size_t)i] = v;
    }
}

extern "C" void kernel_launch(void* const* d_in, const int* in_sizes, int n_in,
                              void* d_out, int out_size, void* d_ws, size_t ws_size,
                              hipStream_t stream) {
    const float* k = (const float*)d_in[0];
    const long long B = in_sizes[0] / 2;     // k is (B,2,1) float32
    long long n4_ll = B * 16;                // 64 floats = 16 float4 per record
    // never exceed the guaranteed out_size floats
    const long long n4_guar = (long long)out_size / 4;
    if (n4_guar > 0 && n4_guar < n4_ll) n4_ll = n4_guar;
    if (n4_ll <= 0) return;
    const int n4 = (int)n4_ll;
    const int block = 256;
    long long grid_ll = (n4_ll + block - 1) / block;
    int grid = (grid_ll > 4096) ? 4096 : (int)grid_ll;
    bulk_hamiltonian_real_kernel<<<grid, block, 0, stream>>>(k, (float4*)d_out, n4);
}